// Round 6
// baseline (4318.035 us; speedup 1.0000x reference)
//
#include <hip/hip_runtime.h>
#include <cstdint>

typedef unsigned u32t;
typedef unsigned long long u64;
typedef float f32x4 __attribute__((ext_vector_type(4)));
typedef short s16x4 __attribute__((ext_vector_type(4)));

#define Qn   515
#define QP   520          // padded cols of A
#define Bn   256
#define Tn   512
#define OQ   516
#define EPSc 1e-16f
#define NSL  65           // real cols per block slice
#define NT   5            // 16-wide n tiles per slice
#define KT   33           // k tiles over padded k space (528/16)
#define KTA  17           // split-K first chunk
#define USTR 532          // ushorts per ustage row (zero-conflict, measured r3)
#define NGRP 32
#define NBLK 8
#define RW   264          // u64 exchange words per batch row (2 bf16 + tag each)

// workspace layout (bytes)
#define WS_AMATH 0                          // 544*260*4 = 565,760
#define WS_INIT  565760                     // 520*4 -> pad to 568,320
#define WS_FBUF  568320                     // 2*32*8*264*8 = 1,081,344
#define WS_CNT   (WS_FBUF + 1081344)        // 8 u32 + pad = 256
#define WS_PAN   (WS_CNT + 256)             // 32 groups * 64B = 2048
#define WS_TOTAL (WS_PAN + 2048)

// LDS layout (bytes)
#define L_FRAG 0
#define L_UST  (NT*KT*64*8)                 // 84,480
#define L_USL  (L_UST + 16*USTR*2)          // +17,024 = 101,504
#define LDS_TOTAL (L_USL + 8*68*4 + 64)     // +2,176+64 = 103,744

__device__ __forceinline__ unsigned bfbits(float x) {
    unsigned u = __builtin_bit_cast(unsigned, x);
    unsigned r = u + 0x7FFFu + ((u >> 16) & 1u);
    return r >> 16;
}
__device__ __forceinline__ float bflo(u32t w) { return __builtin_bit_cast(float, w << 16); }
__device__ __forceinline__ float bfhi(u32t w) { return __builtin_bit_cast(float, w & 0xffff0000u); }

__global__ void prep_A(const float* __restrict__ logA, unsigned* __restrict__ AMATh) {
    __shared__ float red[4];
    __shared__ float srow[Qn];
    int row = blockIdx.x, tid = threadIdx.x;
    if (row >= Qn) {
        for (int c = tid; c < 260; c += 256) AMATh[(size_t)row*260 + c] = 0u;
        return;
    }
    float mx = -1e30f;
    for (int c = tid; c < Qn; c += 256) { float x = logA[(size_t)row*Qn + c]; srow[c] = x; mx = fmaxf(mx, x); }
#pragma unroll
    for (int o = 32; o > 0; o >>= 1) mx = fmaxf(mx, __shfl_xor(mx, o));
    if ((tid & 63) == 0) red[tid >> 6] = mx;
    __syncthreads();
    mx = fmaxf(fmaxf(red[0], red[1]), fmaxf(red[2], red[3]));
    __syncthreads();
    float sm = 0.f;
    for (int c = tid; c < Qn; c += 256) sm += __expf(srow[c] - mx);
#pragma unroll
    for (int o = 32; o > 0; o >>= 1) sm += __shfl_xor(sm, o);
    if ((tid & 63) == 0) red[tid >> 6] = sm;
    __syncthreads();
    float inv = 1.f / (red[0] + red[1] + red[2] + red[3]);
    for (int c2 = tid; c2 < 260; c2 += 256) {
        int c = 2*c2;
        float v0 = (c   < Qn) ? __expf(srow[c]   - mx) * inv : 0.f;
        float v1 = (c+1 < Qn) ? __expf(srow[c+1] - mx) * inv : 0.f;
        AMATh[(size_t)row*260 + c2] = bfbits(v0) | (bfbits(v1) << 16);
    }
}

__global__ void prep_init(const float* __restrict__ il, float* __restrict__ INITD) {
    __shared__ float red[4];
    __shared__ float srow[Qn];
    int tid = threadIdx.x;
    float mx = -1e30f;
    for (int c = tid; c < Qn; c += 256) { float x = il[c]; srow[c] = x; mx = fmaxf(mx, x); }
#pragma unroll
    for (int o = 32; o > 0; o >>= 1) mx = fmaxf(mx, __shfl_xor(mx, o));
    if ((tid & 63) == 0) red[tid >> 6] = mx;
    __syncthreads();
    mx = fmaxf(fmaxf(red[0], red[1]), fmaxf(red[2], red[3]));
    __syncthreads();
    float sm = 0.f;
    for (int c = tid; c < Qn; c += 256) sm += __expf(srow[c] - mx);
#pragma unroll
    for (int o = 32; o > 0; o >>= 1) sm += __shfl_xor(sm, o);
    if ((tid & 63) == 0) red[tid >> 6] = sm;
    __syncthreads();
    float inv = 1.f / (red[0] + red[1] + red[2] + red[3]);
    for (int c = tid; c < 520; c += 256)
        INITD[c] = (c < Qn) ? __expf(srow[c] - mx) * inv : 0.f;
}

__global__ void __launch_bounds__(256, 1)
hmm_fwd(const float* __restrict__ E, const unsigned* __restrict__ AMATh,
        const float* __restrict__ INITD, float* __restrict__ out,
        u64* __restrict__ fbuf, unsigned* __restrict__ cnt,
        unsigned* __restrict__ pan)
{
    extern __shared__ char smem[];
    uint2* frag = (uint2*)(smem + L_FRAG);                    // [NT*KT*64]
    unsigned short* ustage = (unsigned short*)(smem + L_UST); // [16][USTR]
    u32t* ustage32 = (u32t*)ustage;
    float* usl = (float*)(smem + L_USL);                      // [8][68]
    const u64* uslq = (const u64*)usl;                        // row stride 34 u64
    __shared__ unsigned sh_reg[10];                           // x, k, n[0..7]

    const int tid  = threadIdx.x;
    const int lane = tid & 63;
    const int wv   = tid >> 6;

    // ---- registration: discover XCD placement, form XCD-local groups ----
    if (tid == 0) {
        unsigned xcc;
        asm volatile("s_getreg_b32 %0, hwreg(HW_REG_XCC_ID)" : "=s"(xcc));
        xcc &= 7u;
        unsigned k = __hip_atomic_fetch_add(&cnt[xcc], 1u, __ATOMIC_RELAXED, __HIP_MEMORY_SCOPE_AGENT);
        unsigned n[8];
        while (true) {
            unsigned tot = 0;
#pragma unroll
            for (int y = 0; y < 8; ++y) {
                n[y] = __hip_atomic_load(&cnt[y], __ATOMIC_RELAXED, __HIP_MEMORY_SCOPE_AGENT);
                tot += n[y];
            }
            if (tot == 256u) break;
            __builtin_amdgcn_s_sleep(8);
        }
        sh_reg[0] = xcc; sh_reg[1] = k;
#pragma unroll
        for (int y = 0; y < 8; ++y) sh_reg[2+y] = n[y];
    }
    __syncthreads();

    int g, j;
    bool esc;   // escalated = exchange through MALL (sc1); else XCD L2 (sc0)
    {
        unsigned x = sh_reg[0], kk = sh_reg[1];
        unsigned fgx = 0, basex = 0, totalfull = 0, lbefore = 0;
#pragma unroll
        for (unsigned y = 0; y < 8; ++y) {
            unsigned ny = sh_reg[2+y], f = ny >> 3;
            if (y < x) { basex += f; lbefore += ny - (f << 3); }
            if (y == x) fgx = f;
            totalfull += f;
        }
        if (kk < (fgx << 3)) { g = (int)(basex + (kk >> 3)); j = (int)(kk & 7u); esc = false; }
        else {
            unsigned L = lbefore + (kk - (fgx << 3));
            g = (int)(totalfull + (L >> 3)); j = (int)(L & 7u); esc = true;   // cross-XCD group
        }
    }
    const int b0  = g * 8;
    const int q0  = j * NSL;

    // ---- one-time: pack A column-slice into LDS as MFMA B-fragments ----
    for (int f = tid; f < NT*KT*64; f += 256) {
        int tile = f >> 6, l = f & 63;
        int nt = tile / KT, kt = tile - nt*KT;
        int col = q0 + nt*16 + (l & 15);
        int kb  = kt*16 + ((l >> 4) << 2);
        unsigned h[4];
#pragma unroll
        for (int i = 0; i < 4; ++i) {
            int pk_ = kb + i;
            int jr = pk_ / 66, rr = pk_ - jr*66;
            unsigned hv = 0;
            if (rr < 65 && col < QP) {
                int qrow = jr*65 + rr;
                unsigned w = AMATh[(size_t)qrow*260 + (col >> 1)];
                hv = (col & 1) ? (w >> 16) : (w & 0xffffu);
            }
            h[i] = hv;
        }
        uint2 pk;
        pk.x = h[0] | (h[1] << 16);
        pk.y = h[2] | (h[3] << 16);
        frag[f] = pk;
    }
    for (int i = tid; i < 16*(USTR/2); i += 256) ustage32[i] = 0u;

    // ---- per-thread maps ----
    const int ntn = (wv == 0) ? 2 : 1;
    const int nts0 = wv;
    int eoff[2][4];
#pragma unroll
    for (int sl = 0; sl < 2; ++sl) {
#pragma unroll
        for (int r = 0; r < 4; ++r) {
            int nt  = sl ? 4 : nts0;
            int row = ((lane >> 4) << 2) + r;
            int col = nt*16 + (lane & 15);
            int q   = q0 + col;
            bool ok = (lane < 32) && (col < NSL) && (q < Qn) && (sl < ntn);
            eoff[sl][r] = ok ? ((b0 + row)*Qn + q) : -1;
        }
    }
    const int rrow = tid >> 5;     // reader row 0..7
    const int t32  = tid & 31;
    const int nw   = (t32 < 8) ? 9 : 8;

    float llreg = 0.f, lsr = 0.f;
    u64 w9[9];

    // ---- exchange primitives ----
    auto publish = [&](int s) {    // pack usl -> (bf16-pair|tag s+1) -> slot s&1
        u64 tagw = ((u64)(unsigned)(s + 1)) << 32;
        u64* fw = fbuf + ((size_t)(s & 1)*NGRP + g)*(8*RW);
        for (int p = tid; p < 8*33; p += 256) {
            int row = p / 33, c2 = p - row*33;
            u64 uv = uslq[row*34 + c2];
            float a0 = __builtin_bit_cast(float, (unsigned)uv);
            float a1 = __builtin_bit_cast(float, (unsigned)(uv >> 32));
            u64 word = (u64)(bfbits(a0) | (bfbits(a1) << 16)) | tagw;
            u64* ap = fw + (size_t)row*RW + j*33 + c2;
            if (esc) asm volatile("global_store_dwordx2 %0, %1, off sc1" :: "v"(ap), "v"(word) : "memory");
            else     asm volatile("global_store_dwordx2 %0, %1, off sc0" :: "v"(ap), "v"(word) : "memory");
        }
    };

    auto poll_read = [&](int s) -> float {   // wait+read u_{s-1} (tag s) from slot (s-1)&1
        const unsigned want = (unsigned)s;
        const u64* pb = fbuf + (((size_t)((s-1) & 1)*NGRP + g)*8 + rrow)*RW;
        unsigned pend = (t32 < 8) ? 0x1FFu : 0xFFu;
        unsigned it = 0;
        while (pend) {
#pragma unroll
            for (int k = 0; k < 9; ++k) if (pend & (1u << k)) {
                const u64* ap = pb + ((k < 8) ? (t32 + 32*k) : (256 + t32));
                if (esc) asm volatile("global_load_dwordx2 %0, %1, off sc1" : "=v"(w9[k]) : "v"(ap));
                else     asm volatile("global_load_dwordx2 %0, %1, off sc0" : "=v"(w9[k]) : "v"(ap));
            }
            asm volatile("s_waitcnt vmcnt(0)" ::: "memory");
            __builtin_amdgcn_sched_barrier(0);
#pragma unroll
            for (int k = 0; k < 9; ++k)
                if ((pend & (1u << k)) && (unsigned)(w9[k] >> 32) == want) pend &= ~(1u << k);
            ++it;
            if (!esc && pend && (it & 63u) == 0u) {
                // panic protocol: if the L2 fast path is broken, escalate group to MALL
                const unsigned* pp = pan + (unsigned)g*16;
                unsigned pv;
                asm volatile("global_load_dword %0, %1, off sc1" : "=v"(pv) : "v"(pp));
                asm volatile("s_waitcnt vmcnt(0)" ::: "memory");
                __builtin_amdgcn_sched_barrier(0);
                if (!pv && it >= 2048u) {
                    unsigned one = 1u;
                    asm volatile("global_store_dword %0, %1, off sc1" :: "v"(pp), "v"(one) : "memory");
                    pv = 1u;
                }
                if (pv) {
                    esc = true;
                    // republish my own last-published words (usl holds u_{s-1}) via MALL
                    u64 tagw = ((u64)want) << 32;
                    u64* fw = fbuf + ((size_t)((s-1) & 1)*NGRP + g)*(8*RW);
                    for (int p = tid; p < 8*33; p += 256) {
                        int row = p / 33, c2 = p - row*33;
                        u64 uv = uslq[row*34 + c2];
                        float a0 = __builtin_bit_cast(float, (unsigned)uv);
                        float a1 = __builtin_bit_cast(float, (unsigned)(uv >> 32));
                        u64 word = (u64)(bfbits(a0) | (bfbits(a1) << 16)) | tagw;
                        u64* ap = fw + (size_t)row*RW + j*33 + c2;
                        asm volatile("global_store_dwordx2 %0, %1, off sc1" :: "v"(ap), "v"(word) : "memory");
                    }
                }
            }
        }
        float sum = 0.f;
#pragma unroll
        for (int k = 0; k < 9; ++k) {
            if (k < nw) { u32t pr = (u32t)w9[k]; sum += bflo(pr) + bfhi(pr); }
        }
#pragma unroll
        for (int o = 1; o < 32; o <<= 1) sum += __shfl_xor(sum, o);
        lsr = __logf(sum);
        llreg += lsr;
        return 1.f / sum;
    };

    auto stage = [&](float iv) {   // normalized bf16 -> ustage (own words only)
#pragma unroll
        for (int k = 0; k < 9; ++k) {
            if (k < nw) {
                int wi = (k < 8) ? (t32 + 32*k) : (256 + t32);
                u32t pr = (u32t)w9[k];
                ustage32[rrow*(USTR/2) + wi] = bfbits(bflo(pr)*iv) | (bfbits(bfhi(pr)*iv) << 16);
            }
        }
    };

    auto emit_outputs = [&](int tOut) {
        if (t32 == 0 && j == 0)
            out[((size_t)(b0 + rrow)*Tn + tOut)*OQ + Qn] = llreg;
        float* orow = out + ((size_t)(b0 + rrow)*Tn + tOut)*OQ;
#pragma unroll
        for (int k = 0; k < 9; ++k) {
            if (k < nw) {
                int wi = (k < 8) ? (t32 + 32*k) : (256 + t32);
                u32t pr = (u32t)w9[k];
                int c0 = 2*wi;
#pragma unroll
                for (int h = 0; h < 2; ++h) {
                    int c = c0 + h;
                    int jr = c / 66, loc = c - jr*66;
                    if (jr == j && loc < 65) {
                        int q = q0 + loc;
                        if (q < Qn) {
                            float f = h ? bfhi(pr) : bflo(pr);
                            orow[q] = __logf(f) - lsr;
                        }
                    }
                }
            }
        }
    };

    // ---- t = 0 : u0 = max(E0,eps) * max(init,eps) -> usl -> publish ----
    for (int p = tid; p < 8*66; p += 256) {
        int row = p / 66, c = p - row*66;
        int q = q0 + c;
        float uv = 0.f;
        if (c < 65 && q < Qn)
            uv = fmaxf(E[(size_t)(b0+row)*Qn + q], EPSc) * fmaxf(INITD[q], EPSc);
        usl[row*68 + c] = uv;    // col 65 pad stays 0 forever
    }
    __syncthreads();
    publish(0);

    // ---- main loop ----
    for (int s = 1; s < Tn; ++s) {
        // prefetch E_s (HBM latency hides under the poll)
        float ev[2][4];
        size_t ebase = (size_t)s * Bn * Qn;
#pragma unroll
        for (int sl = 0; sl < 2; ++sl)
#pragma unroll
            for (int r = 0; r < 4; ++r)
                ev[sl][r] = (eoff[sl][r] >= 0) ? E[ebase + eoff[sl][r]] : 0.f;

        float iv = poll_read(s);
        stage(iv);
        __syncthreads();    // ustage visible (prev MFMA finished before prev end-barrier)

        // MFMA: R = a_{s-1} (16xK, rows 8..15 zero) @ Aslice (KxN), split-K x2
        f32x4 a0a = {0.f,0.f,0.f,0.f}, a0b = {0.f,0.f,0.f,0.f};
        f32x4 a1a = {0.f,0.f,0.f,0.f}, a1b = {0.f,0.f,0.f,0.f};
        {
            const unsigned short* urow = ustage + (lane & 15)*USTR + ((lane >> 4) << 2);
            const uint2* f0 = frag + (size_t)(nts0*KT)*64 + lane;
            const uint2* f1 = frag + (size_t)(4*KT)*64 + lane;
#pragma unroll 2
            for (int kt = 0; kt < KTA; ++kt) {
                s16x4 af = __builtin_bit_cast(s16x4, *(const uint2*)(urow + kt*16));
                a0a = __builtin_amdgcn_mfma_f32_16x16x16bf16_1k(af, __builtin_bit_cast(s16x4, f0[kt*64]), a0a, 0, 0, 0);
                if (ntn == 2)
                    a1a = __builtin_amdgcn_mfma_f32_16x16x16bf16_1k(af, __builtin_bit_cast(s16x4, f1[kt*64]), a1a, 0, 0, 0);
                int k2 = kt + KTA;
                if (k2 < KT) {
                    s16x4 af2 = __builtin_bit_cast(s16x4, *(const uint2*)(urow + k2*16));
                    a0b = __builtin_amdgcn_mfma_f32_16x16x16bf16_1k(af2, __builtin_bit_cast(s16x4, f0[k2*64]), a0b, 0, 0, 0);
                    if (ntn == 2)
                        a1b = __builtin_amdgcn_mfma_f32_16x16x16bf16_1k(af2, __builtin_bit_cast(s16x4, f1[k2*64]), a1b, 0, 0, 0);
                }
            }
        }
        // epilogue: u_s = max(E,eps) * max(R,eps) -> usl
        if (lane < 32) {
#pragma unroll
            for (int r = 0; r < 4; ++r) {
                int row = ((lane >> 4) << 2) + r;
                {
                    int col = nts0*16 + (lane & 15);
                    if (col < NSL) {
                        float R = fmaxf(a0a[r] + a0b[r], EPSc);
                        int q = q0 + col;
                        usl[row*68 + col] = (q < Qn) ? fmaxf(ev[0][r], EPSc) * R : 0.f;
                    }
                }
                if (ntn == 2) {
                    int col = 64 + (lane & 15);
                    if (col < NSL) {
                        float R = fmaxf(a1a[r] + a1b[r], EPSc);
                        int q = q0 + col;
                        usl[row*68 + col] = (q < Qn) ? fmaxf(ev[1][r], EPSc) * R : 0.f;
                    }
                }
            }
        }
        __syncthreads();    // usl complete; all waves past MFMA
        publish(s);
        emit_outputs(s - 1);  // off the inter-block critical path
    }

    // ---- tail: t = 511 ----
    poll_read(Tn);
    emit_outputs(Tn - 1);
}

extern "C" void kernel_launch(void* const* d_in, const int* in_sizes, int n_in,
                              void* d_out, int out_size, void* d_ws, size_t ws_size,
                              hipStream_t stream) {
    (void)in_sizes; (void)n_in; (void)out_size;
    if (ws_size < (size_t)WS_TOTAL) return;

    const float* E    = (const float*)d_in[0];
    const float* logA = (const float*)d_in[1];
    const float* il   = (const float*)d_in[2];
    float* out = (float*)d_out;
    char*  ws  = (char*)d_ws;

    unsigned* AMATh = (unsigned*)(ws + WS_AMATH);
    float*    INITD = (float*)(ws + WS_INIT);
    u64*      fbuf  = (u64*)(ws + WS_FBUF);
    unsigned* cnt   = (unsigned*)(ws + WS_CNT);
    unsigned* pan   = (unsigned*)(ws + WS_PAN);

    // exchange tags, registration counters, panic words: zero every launch/replay
    hipMemsetAsync(ws + WS_FBUF, 0, WS_TOTAL - WS_FBUF, stream);

    prep_A<<<544, 256, 0, stream>>>(logA, AMATh);
    prep_init<<<1, 256, 0, stream>>>(il, INITD);

    static_assert(LDS_TOTAL < 160*1024, "LDS budget");
    hipFuncSetAttribute(reinterpret_cast<const void*>(hmm_fwd),
                        hipFuncAttributeMaxDynamicSharedMemorySize, LDS_TOTAL);
    hmm_fwd<<<256, 256, LDS_TOTAL, stream>>>(E, AMATh, INITD, out, fbuf, cnt, pan);
}